// Round 1
// baseline (9649.773 us; speedup 1.0000x reference)
//
#include <hip/hip_runtime.h>

typedef unsigned int u32;
typedef unsigned short u16;
typedef unsigned long long u64;

// ---------------- problem constants ----------------
// B=2048, CIN=256, NH=512, NF=112, K=112, NL=50, MC=100, NOUT=200
// out (f32 elements): c_prob [2048,112,100] | y [2048,200] | c_hard [2048,112,100]
#define YOFF  22937600ull
#define CHOFF 23347200ull

// workspace offsets (bytes) — total ~9.3 MB
#define OFF_HA    0ull          // 2048*512 f32 = 4,194,304 B
#define OFF_HB    4194304ull    // 2048*512 f32
#define OFF_INTER 8388608ull    // 2048*112 f32 = 917,504 B

// ---------------- threefry2x32 (JAX-compatible, partitionable stream) ----------------
__host__ __device__ inline u32 rotl32_(u32 x, int r) { return (x << r) | (x >> (32 - r)); }
__host__ __device__ inline void tf2x32(u32 k0, u32 k1, u32 c0, u32 c1, u32& o0, u32& o1) {
  u32 ks0 = k0, ks1 = k1, ks2 = k0 ^ k1 ^ 0x1BD11BDAu;
  u32 x0 = c0 + ks0, x1 = c1 + ks1;
  const int RA[4] = {13, 15, 26, 6}, RB[4] = {17, 29, 16, 24};
  for (int i = 0; i < 5; ++i) {
    const int* R = (i & 1) ? RB : RA;
    for (int j = 0; j < 4; ++j) { x0 += x1; x1 = rotl32_(x1, R[j]); x1 ^= x0; }
    switch (i) {
      case 0: x0 += ks1; x1 += ks2 + 1u; break;
      case 1: x0 += ks2; x1 += ks0 + 2u; break;
      case 2: x0 += ks0; x1 += ks1 + 3u; break;
      case 3: x0 += ks1; x1 += ks2 + 4u; break;
      case 4: x0 += ks2; x1 += ks0 + 5u; break;
    }
  }
  o0 = x0; o1 = x1;
}

struct SKeys { u32 v[224]; };  // per-step subkeys: sk_i = tf(key_i,(0,1)); key_{i+1} = tf(key_i,(0,0))

// ---------------- generic f32 GEMM: C = act(A@B + bias) ----------------
// 64x64 tile, BK=32, 256 threads, 4x4 per thread.
template <bool DO_LRELU>
__global__ __launch_bounds__(256) void gemm_bias(const float* __restrict__ A,
                                                 const float* __restrict__ Bm,
                                                 const float* __restrict__ bias,
                                                 float* __restrict__ C,
                                                 int M, int N, int K) {
  __shared__ float As[32][65];  // [k][m]
  __shared__ float Bs[32][65];  // [k][n]
  const int bm = blockIdx.y * 64, bn = blockIdx.x * 64;
  const int t = threadIdx.x;
  const int ty = t >> 4, tx = t & 15;
  float acc[4][4] = {};
  for (int k0 = 0; k0 < K; k0 += 32) {
#pragma unroll
    for (int l = 0; l < 2; ++l) {
      int e = l * 256 + t;                // < 512
      int m = e >> 3, k4 = e & 7;         // 64 rows x 8 float4
      float4 v = *(const float4*)(A + (size_t)(bm + m) * K + (k0 + k4 * 4));
      As[k4 * 4 + 0][m] = v.x; As[k4 * 4 + 1][m] = v.y;
      As[k4 * 4 + 2][m] = v.z; As[k4 * 4 + 3][m] = v.w;
    }
#pragma unroll
    for (int l = 0; l < 2; ++l) {
      int e = l * 256 + t;
      int k = e >> 4, n4 = e & 15;        // 32 k x 16 float4
      int gn = bn + n4 * 4;
      if (gn < N) {
        float4 v = *(const float4*)(Bm + (size_t)(k0 + k) * N + gn);
        Bs[k][n4 * 4 + 0] = v.x; Bs[k][n4 * 4 + 1] = v.y;
        Bs[k][n4 * 4 + 2] = v.z; Bs[k][n4 * 4 + 3] = v.w;
      } else {
        Bs[k][n4 * 4 + 0] = 0.f; Bs[k][n4 * 4 + 1] = 0.f;
        Bs[k][n4 * 4 + 2] = 0.f; Bs[k][n4 * 4 + 3] = 0.f;
      }
    }
    __syncthreads();
#pragma unroll
    for (int kk = 0; kk < 32; ++kk) {
      float a[4], b[4];
#pragma unroll
      for (int j = 0; j < 4; ++j) { a[j] = As[kk][ty * 4 + j]; b[j] = Bs[kk][tx * 4 + j]; }
#pragma unroll
      for (int i = 0; i < 4; ++i)
#pragma unroll
        for (int j = 0; j < 4; ++j) acc[i][j] = fmaf(a[i], b[j], acc[i][j]);
    }
    __syncthreads();
  }
#pragma unroll
  for (int i = 0; i < 4; ++i) {
#pragma unroll
    for (int j = 0; j < 4; ++j) {
      int m = bm + ty * 4 + i, n = bn + tx * 4 + j;
      if (n < N) {
        float s = acc[i][j] + bias[n];
        if (DO_LRELU) { if (s < 0.f) s = 0.01f * s; }
        C[(size_t)m * N + n] = s;
      }
    }
  }
}

// ---------------- base_i[b][h] = inter @ W1_i[:112,:] + b1_i  -> stored into out c_hard region ----------------
// block: 64 b x 50 h, fixed i = blockIdx.y. Stored at out[CHOFF + b*11200 + i*100 + h] (h<50),
// consumed by sample_kernel2; c_hard region is only rewritten by expand_kernel afterwards.
__global__ __launch_bounds__(256) void base_kernel(const float* __restrict__ inter,
                                                   const float* __restrict__ W1,
                                                   const float* __restrict__ pb1,
                                                   float* __restrict__ out) {
  __shared__ float As[112][65];  // [k][b]
  __shared__ float Ws[112][64];  // [k][h], zero-padded h>=50
  const int i = blockIdx.y;
  const int b0 = blockIdx.x * 64;
  const int t = threadIdx.x;
  const int ty = t >> 4, tx = t & 15;
#pragma unroll
  for (int l = 0; l < 7; ++l) {
    int e4 = l * 256 + t;               // < 1792 = 64 rows * 28 float4
    int k4 = e4 % 28, bs = e4 / 28;
    float4 v = *(const float4*)(inter + (size_t)(b0 + bs) * 112 + k4 * 4);
    As[k4 * 4 + 0][bs] = v.x; As[k4 * 4 + 1][bs] = v.y;
    As[k4 * 4 + 2][bs] = v.z; As[k4 * 4 + 3][bs] = v.w;
  }
#pragma unroll
  for (int l = 0; l < 28; ++l) {
    int e = l * 256 + t;                // < 7168 = 112*64
    int r = e >> 6, c = e & 63;
    Ws[r][c] = (c < 50) ? W1[(size_t)i * 11200 + r * 50 + c] : 0.f;
  }
  __syncthreads();
  float acc[4][4] = {};
  for (int kk = 0; kk < 112; ++kk) {
    float a[4], b[4];
#pragma unroll
    for (int j = 0; j < 4; ++j) { a[j] = As[kk][ty * 4 + j]; b[j] = Ws[kk][tx * 4 + j]; }
#pragma unroll
    for (int ii = 0; ii < 4; ++ii)
#pragma unroll
      for (int j = 0; j < 4; ++j) acc[ii][j] = fmaf(a[ii], b[j], acc[ii][j]);
  }
#pragma unroll
  for (int ii = 0; ii < 4; ++ii) {
#pragma unroll
    for (int j = 0; j < 4; ++j) {
      int b = b0 + ty * 4 + ii, h = tx * 4 + j;
      if (h < 50) {
        out[CHOFF + (size_t)b * 11200 + (size_t)i * 100 + h] = acc[ii][j] + pb1[i * 50 + h];
      }
    }
  }
}

// ---------------- sequential concept sampling: TWO THREADS PER PAIR (h-split 25+25) ----------------
// 256-thread blocks = 4 waves; waves 0,1 handle h[0:25) ("sub0"), waves 2,3 handle h[25:50)
// ("sub1") for the same 128 pairs. sub is wave-uniform, so the feedback-weight reads stay
// wave-uniform (s_load). Grid = 1600 blocks x 4 waves = 6400 waves (~78% occupancy vs the old
// 410x8 = 3280 = 40% grid-limited launch). The per-h accumulator chains and the final
// sequential 50-term dot (executed entirely on sub0, with sub1's lrelu'd values passed via
// LDS) are BITWISE IDENTICAL to the 1-thread-per-pair version, so sampling cannot flip.
// sub1 computes the threefry uniform (independent of the dot) to balance the tails.
// c_hard is NOT written here (pairs of one batch span blocks -> would race with the base rows
// staged in the c_hard region). Instead the two u64 history masks are written to the unused
// m>=50 cells of c_hard rows i=0..7 and expanded by expand_kernel afterwards.
__global__ __launch_bounds__(256, 7) void sample_kernel2(const float* __restrict__ W1,
                                                         const float* __restrict__ W2,
                                                         const float* __restrict__ b2,
                                                         float* __restrict__ out, SKeys sks) {
  __shared__ float vbuf[128][26];   // [q][0..24] = v(h=25..49); [q][25] = rng uniform u
  __shared__ u32 bitbuf[128];
  const int t = threadIdx.x;
  const int w = t >> 6;
  const int lane = t & 63;
  const int sub = w >> 1;                       // waves 0,1 -> 0; waves 2,3 -> 1 (wave-uniform)
  const int q = ((w & 1) << 6) | lane;          // local pair 0..127
  const int p = blockIdx.x * 128 + q;           // global pair = b*100 + m
  const int b = p / 100;
  const int m = p - b * 100;
  const float* __restrict__ baserow = out + CHOFF + (size_t)b * 11200;
  u64 lo = 0, hi = 0;

  for (int i = 0; i < 112; ++i) {
    const float* __restrict__ Wi = W1 + (size_t)i * 11200 + 5600 + sub * 25;  // wave-uniform
    float acc[25];
#pragma unroll
    for (int h = 0; h < 25; ++h) acc[h] = 0.f;
    // r-loop: acc[h] += c_r * W[r][h]; per-h order identical to the 1-thread version
    {
      int r = 0;
      int r1 = (i < 64) ? i : 64;
      u64 cm = lo;
      for (; r < r1; ++r) {
        float c = (cm & 1ull) ? 1.f : 0.f;
        cm >>= 1;
        const float* __restrict__ wr = Wi + r * 50;   // wave-uniform -> s_load
#pragma unroll
        for (int h = 0; h < 25; ++h) acc[h] = fmaf(c, wr[h], acc[h]);
      }
      cm = hi;
      for (; r < i; ++r) {
        float c = (cm & 1ull) ? 1.f : 0.f;
        cm >>= 1;
        const float* __restrict__ wr = Wi + r * 50;
#pragma unroll
        for (int h = 0; h < 25; ++h) acc[h] = fmaf(c, wr[h], acc[h]);
      }
    }
    const float* bs = baserow + (size_t)i * 100 + sub * 25;
    if (sub) {
      // v[h] = lrelu(acc+base) for global h=25..49, ship to sub0 via LDS (float2-packed,
      // stride 26 floats -> 2-way bank aliasing only, free on CDNA4)
#pragma unroll
      for (int h2 = 0; h2 < 12; ++h2) {
        float v0 = acc[2 * h2] + bs[2 * h2];         if (v0 < 0.f) v0 = 0.01f * v0;
        float v1 = acc[2 * h2 + 1] + bs[2 * h2 + 1]; if (v1 < 0.f) v1 = 0.01f * v1;
        *(float2*)&vbuf[q][2 * h2] = make_float2(v0, v1);
      }
      {
        float v24 = acc[24] + bs[24]; if (v24 < 0.f) v24 = 0.01f * v24;
        vbuf[q][24] = v24;
      }
      // rng uniform (independent of the dot) computed here to balance the tails
      u32 a0, a1;
      tf2x32(sks.v[2 * i], sks.v[2 * i + 1], 0u, (u32)p, a0, a1);
      u32 fb = ((a0 ^ a1) >> 9) | 0x3F800000u;
      float u; __builtin_memcpy(&u, &fb, 4); u -= 1.f;
      vbuf[q][25] = u;
    }
    __syncthreads();   // barrier A: vbuf(i) ready
    if (!sub) {
      const float* __restrict__ w2 = W2 + i * 50;   // wave-uniform
      float s = 0.f;
#pragma unroll
      for (int h = 0; h < 25; ++h) {
        float v = acc[h] + bs[h];
        if (v < 0.f) v = 0.01f * v;
        s = fmaf(v, w2[h], s);
      }
#pragma unroll
      for (int h2 = 0; h2 < 12; ++h2) {
        float2 vv = *(const float2*)&vbuf[q][2 * h2];
        s = fmaf(vv.x, w2[25 + 2 * h2], s);
        s = fmaf(vv.y, w2[26 + 2 * h2], s);
      }
      s = fmaf(vbuf[q][24], w2[49], s);
      float l = s + b2[i];
      float pr = 1.f / (1.f + expf(-l));
      float u = vbuf[q][25];
      u32 smp = (u < pr) ? 1u : 0u;
      out[(size_t)b * 11200 + (size_t)i * 100 + m] = pr;   // c_prob (owned cell)
      bitbuf[q] = smp;
    }
    __syncthreads();   // barrier B: bit(i) ready; also fences vbuf reuse for i+1
    u32 bit = bitbuf[q];
    if (bit) { if (i < 64) lo |= 1ull << i; else hi |= 1ull << (i - 64); }
  }
  // store the two u64 masks into the never-staged m>=50 cells of c_hard rows 0..7
  if (!sub) {
    u32* ob = (u32*)out;
    size_t cb = CHOFF + (size_t)b * 11200 + (size_t)((m >= 50) ? 4 : 0) * 100 + 50 + (m % 50);
    ob[cb + 0]   = (u32)lo;
    ob[cb + 100] = (u32)(lo >> 32);
    ob[cb + 200] = (u32)hi;
    ob[cb + 300] = (u32)(hi >> 32);
  }
}

// ---------------- expand masks -> c_hard (memory-bound, ~30 us) ----------------
// one block per batch b; reads the packed masks (before any write), then writes all 11200 cells
__global__ __launch_bounds__(256) void expand_kernel(float* __restrict__ out) {
  __shared__ u32 mW[100][4];
  const int b = blockIdx.x;
  const int t = threadIdx.x;
  const u32* ob = (const u32*)out;
  if (t < 100) {
    size_t cb = CHOFF + (size_t)b * 11200 + (size_t)((t >= 50) ? 4 : 0) * 100 + 50 + (t % 50);
    mW[t][0] = ob[cb + 0];
    mW[t][1] = ob[cb + 100];
    mW[t][2] = ob[cb + 200];
    mW[t][3] = ob[cb + 300];
  }
  __syncthreads();
  for (int e = t; e < 11200; e += 256) {
    int i = e / 100, m = e - i * 100;
    u32 word = mW[m][i >> 5];
    out[CHOFF + (size_t)b * 11200 + e] = (float)((word >> (i & 31)) & 1u);
  }
}

// ---------------- head: logits -> softmax -> mean over m -> log ----------------
// one block per b; 256 threads
__global__ __launch_bounds__(256) void head_kernel(const float* __restrict__ HW,
                                                   const float* __restrict__ hb,
                                                   float* __restrict__ out) {
  __shared__ unsigned char cS[100][116];
  __shared__ float lgS[50][201];
  const int b = blockIdx.x;
  const int t = threadIdx.x;
  for (int e = t; e < 11200; e += 256) {
    int k = e / 100, m = e - k * 100;
    cS[m][k] = (out[CHOFF + (size_t)b * 11200 + (size_t)k * 100 + m] != 0.f) ? 1 : 0;
  }
  __syncthreads();
  float pacc = 0.f;
  for (int mh = 0; mh < 2; ++mh) {
    for (int l = 0; l < 3; ++l) {
      int tile = l * 256 + t;
      if (tile < 625) {                    // 25 o-chunks x 25 m-chunks
        int o0 = (tile % 25) * 8;
        int m0 = (tile / 25) * 2;
        float acc[2][8] = {};
        for (int k = 0; k < 112; ++k) {
          float4 wa = *(const float4*)(HW + (size_t)k * 200 + o0);
          float4 wb = *(const float4*)(HW + (size_t)k * 200 + o0 + 4);
          float w[8] = {wa.x, wa.y, wa.z, wa.w, wb.x, wb.y, wb.z, wb.w};
          float c0 = (float)cS[mh * 50 + m0][k];
          float c1 = (float)cS[mh * 50 + m0 + 1][k];
#pragma unroll
          for (int jo = 0; jo < 8; ++jo) {
            acc[0][jo] = fmaf(c0, w[jo], acc[0][jo]);
            acc[1][jo] = fmaf(c1, w[jo], acc[1][jo]);
          }
        }
#pragma unroll
        for (int im = 0; im < 2; ++im)
#pragma unroll
          for (int jo = 0; jo < 8; ++jo) {
            int o = o0 + jo;
            lgS[m0 + im][o] = acc[im][jo] + hb[o];
          }
      }
    }
    __syncthreads();
    if (t < 50) {
      int m = t;
      float mx = -3.0e38f;
      for (int o = 0; o < 200; ++o) mx = fmaxf(mx, lgS[m][o]);
      float s = 0.f;
      for (int o = 0; o < 200; ++o) {
        float e = expf(lgS[m][o] - mx);
        lgS[m][o] = e; s += e;
      }
      float inv = 1.f / s;
      for (int o = 0; o < 200; ++o) lgS[m][o] = lgS[m][o] * inv;
    }
    __syncthreads();
    if (t < 200) { for (int m = 0; m < 50; ++m) pacc += lgS[m][t]; }
    __syncthreads();
  }
  if (t < 200) {
    out[YOFF + (size_t)b * 200 + t] = logf(pacc / 100.f + 1e-6f);
  }
}

// ---------------- launcher ----------------
extern "C" void kernel_launch(void* const* d_in, const int* in_sizes, int n_in,
                              void* d_out, int out_size, void* d_ws, size_t ws_size,
                              hipStream_t stream) {
  const float* x    = (const float*)d_in[0];
  const float* Win  = (const float*)d_in[1];
  const float* bin  = (const float*)d_in[2];
  const float* Wh   = (const float*)d_in[3];
  const float* bh   = (const float*)d_in[4];
  const float* Wout = (const float*)d_in[5];
  const float* bout = (const float*)d_in[6];
  const float* pW1  = (const float*)d_in[7];
  const float* pb1  = (const float*)d_in[8];
  const float* pW2  = (const float*)d_in[9];
  const float* pb2  = (const float*)d_in[10];
  const float* hW   = (const float*)d_in[11];
  const float* hb   = (const float*)d_in[12];
  float* out = (float*)d_out;
  char* ws = (char*)d_ws;

  float* hA     = (float*)(ws + OFF_HA);
  float* hB     = (float*)(ws + OFF_HB);
  float* interB = (float*)(ws + OFF_INTER);

  gemm_bias<true ><<<dim3(8, 32), 256, 0, stream>>>(x,  Win,             bin,          hA,     2048, 512, 256);
  gemm_bias<true ><<<dim3(8, 32), 256, 0, stream>>>(hA, Wh + 0 * 262144, bh + 0 * 512, hB,     2048, 512, 512);
  gemm_bias<true ><<<dim3(8, 32), 256, 0, stream>>>(hB, Wh + 1 * 262144, bh + 1 * 512, hA,     2048, 512, 512);
  gemm_bias<true ><<<dim3(8, 32), 256, 0, stream>>>(hA, Wh + 2 * 262144, bh + 2 * 512, hB,     2048, 512, 512);
  gemm_bias<true ><<<dim3(8, 32), 256, 0, stream>>>(hB, Wh + 3 * 262144, bh + 3 * 512, hA,     2048, 512, 512);
  gemm_bias<false><<<dim3(2, 32), 256, 0, stream>>>(hA, Wout,            bout,         interB, 2048, 112, 512);

  base_kernel<<<dim3(32, 112), 256, 0, stream>>>(interB, pW1, pb1, out);

  // host-side key chain: key(42)=(0,42); partitionable split: key'=tf(key,(0,0)), sk=tf(key,(0,1))
  SKeys sks;
  {
    u32 k0 = 0u, k1 = 42u;
    for (int i = 0; i < 112; ++i) {
      u32 nk0, nk1, s0, s1;
      tf2x32(k0, k1, 0u, 0u, nk0, nk1);
      tf2x32(k0, k1, 0u, 1u, s0, s1);
      sks.v[2 * i] = s0; sks.v[2 * i + 1] = s1;
      k0 = nk0; k1 = nk1;
    }
  }
  sample_kernel2<<<1600, 256, 0, stream>>>(pW1, pW2, pb2, out, sks);
  expand_kernel<<<2048, 256, 0, stream>>>(out);

  head_kernel<<<2048, 256, 0, stream>>>(hW, hb, out);
}

// Round 2
// 8867.023 us; speedup vs baseline: 1.0883x; 1.0883x over previous
//
#include <hip/hip_runtime.h>

typedef unsigned int u32;
typedef unsigned short u16;
typedef unsigned long long u64;

// ---------------- problem constants ----------------
// B=2048, CIN=256, NH=512, NF=112, K=112, NL=50, MC=100, NOUT=200
// out (f32 elements): c_prob [2048,112,100] | y [2048,200] | c_hard [2048,112,100]
#define YOFF  22937600ull
#define CHOFF 23347200ull

// workspace offsets (bytes) — total ~9.3 MB
#define OFF_HA    0ull          // 2048*512 f32 = 4,194,304 B
#define OFF_HB    4194304ull    // 2048*512 f32
#define OFF_INTER 8388608ull    // 2048*112 f32 = 917,504 B

// ---------------- threefry2x32 (JAX-compatible, partitionable stream) ----------------
__host__ __device__ inline u32 rotl32_(u32 x, int r) { return (x << r) | (x >> (32 - r)); }
__host__ __device__ inline void tf2x32(u32 k0, u32 k1, u32 c0, u32 c1, u32& o0, u32& o1) {
  u32 ks0 = k0, ks1 = k1, ks2 = k0 ^ k1 ^ 0x1BD11BDAu;
  u32 x0 = c0 + ks0, x1 = c1 + ks1;
  const int RA[4] = {13, 15, 26, 6}, RB[4] = {17, 29, 16, 24};
  for (int i = 0; i < 5; ++i) {
    const int* R = (i & 1) ? RB : RA;
    for (int j = 0; j < 4; ++j) { x0 += x1; x1 = rotl32_(x1, R[j]); x1 ^= x0; }
    switch (i) {
      case 0: x0 += ks1; x1 += ks2 + 1u; break;
      case 1: x0 += ks2; x1 += ks0 + 2u; break;
      case 2: x0 += ks0; x1 += ks1 + 3u; break;
      case 3: x0 += ks1; x1 += ks2 + 4u; break;
      case 4: x0 += ks2; x1 += ks0 + 5u; break;
    }
  }
  o0 = x0; o1 = x1;
}

struct SKeys { u32 v[224]; };  // per-step subkeys: sk_i = tf(key_i,(0,1)); key_{i+1} = tf(key_i,(0,0))

// ---------------- generic f32 GEMM: C = act(A@B + bias) ----------------
// 64x64 tile, BK=32, 256 threads, 4x4 per thread.
template <bool DO_LRELU>
__global__ __launch_bounds__(256) void gemm_bias(const float* __restrict__ A,
                                                 const float* __restrict__ Bm,
                                                 const float* __restrict__ bias,
                                                 float* __restrict__ C,
                                                 int M, int N, int K) {
  __shared__ float As[32][65];  // [k][m]
  __shared__ float Bs[32][65];  // [k][n]
  const int bm = blockIdx.y * 64, bn = blockIdx.x * 64;
  const int t = threadIdx.x;
  const int ty = t >> 4, tx = t & 15;
  float acc[4][4] = {};
  for (int k0 = 0; k0 < K; k0 += 32) {
#pragma unroll
    for (int l = 0; l < 2; ++l) {
      int e = l * 256 + t;                // < 512
      int m = e >> 3, k4 = e & 7;         // 64 rows x 8 float4
      float4 v = *(const float4*)(A + (size_t)(bm + m) * K + (k0 + k4 * 4));
      As[k4 * 4 + 0][m] = v.x; As[k4 * 4 + 1][m] = v.y;
      As[k4 * 4 + 2][m] = v.z; As[k4 * 4 + 3][m] = v.w;
    }
#pragma unroll
    for (int l = 0; l < 2; ++l) {
      int e = l * 256 + t;
      int k = e >> 4, n4 = e & 15;        // 32 k x 16 float4
      int gn = bn + n4 * 4;
      if (gn < N) {
        float4 v = *(const float4*)(Bm + (size_t)(k0 + k) * N + gn);
        Bs[k][n4 * 4 + 0] = v.x; Bs[k][n4 * 4 + 1] = v.y;
        Bs[k][n4 * 4 + 2] = v.z; Bs[k][n4 * 4 + 3] = v.w;
      } else {
        Bs[k][n4 * 4 + 0] = 0.f; Bs[k][n4 * 4 + 1] = 0.f;
        Bs[k][n4 * 4 + 2] = 0.f; Bs[k][n4 * 4 + 3] = 0.f;
      }
    }
    __syncthreads();
#pragma unroll
    for (int kk = 0; kk < 32; ++kk) {
      float a[4], b[4];
#pragma unroll
      for (int j = 0; j < 4; ++j) { a[j] = As[kk][ty * 4 + j]; b[j] = Bs[kk][tx * 4 + j]; }
#pragma unroll
      for (int i = 0; i < 4; ++i)
#pragma unroll
        for (int j = 0; j < 4; ++j) acc[i][j] = fmaf(a[i], b[j], acc[i][j]);
    }
    __syncthreads();
  }
#pragma unroll
  for (int i = 0; i < 4; ++i) {
#pragma unroll
    for (int j = 0; j < 4; ++j) {
      int m = bm + ty * 4 + i, n = bn + tx * 4 + j;
      if (n < N) {
        float s = acc[i][j] + bias[n];
        if (DO_LRELU) { if (s < 0.f) s = 0.01f * s; }
        C[(size_t)m * N + n] = s;
      }
    }
  }
}

// ---------------- base_i[b][h] = inter @ W1_i[:112,:] + b1_i  -> stored into out c_hard region ----------------
// block: 64 b x 50 h, fixed i = blockIdx.y. Stored at out[CHOFF + b*11200 + i*100 + h] (h<50),
// consumed by sample_kernel3; c_hard region is only rewritten by expand_kernel afterwards.
__global__ __launch_bounds__(256) void base_kernel(const float* __restrict__ inter,
                                                   const float* __restrict__ W1,
                                                   const float* __restrict__ pb1,
                                                   float* __restrict__ out) {
  __shared__ float As[112][65];  // [k][b]
  __shared__ float Ws[112][64];  // [k][h], zero-padded h>=50
  const int i = blockIdx.y;
  const int b0 = blockIdx.x * 64;
  const int t = threadIdx.x;
  const int ty = t >> 4, tx = t & 15;
#pragma unroll
  for (int l = 0; l < 7; ++l) {
    int e4 = l * 256 + t;               // < 1792 = 64 rows * 28 float4
    int k4 = e4 % 28, bs = e4 / 28;
    float4 v = *(const float4*)(inter + (size_t)(b0 + bs) * 112 + k4 * 4);
    As[k4 * 4 + 0][bs] = v.x; As[k4 * 4 + 1][bs] = v.y;
    As[k4 * 4 + 2][bs] = v.z; As[k4 * 4 + 3][bs] = v.w;
  }
#pragma unroll
  for (int l = 0; l < 28; ++l) {
    int e = l * 256 + t;                // < 7168 = 112*64
    int r = e >> 6, c = e & 63;
    Ws[r][c] = (c < 50) ? W1[(size_t)i * 11200 + r * 50 + c] : 0.f;
  }
  __syncthreads();
  float acc[4][4] = {};
  for (int kk = 0; kk < 112; ++kk) {
    float a[4], b[4];
#pragma unroll
    for (int j = 0; j < 4; ++j) { a[j] = As[kk][ty * 4 + j]; b[j] = Ws[kk][tx * 4 + j]; }
#pragma unroll
    for (int ii = 0; ii < 4; ++ii)
#pragma unroll
      for (int j = 0; j < 4; ++j) acc[ii][j] = fmaf(a[ii], b[j], acc[ii][j]);
  }
#pragma unroll
  for (int ii = 0; ii < 4; ++ii) {
#pragma unroll
    for (int j = 0; j < 4; ++j) {
      int b = b0 + ty * 4 + ii, h = tx * 4 + j;
      if (h < 50) {
        out[CHOFF + (size_t)b * 11200 + (size_t)i * 100 + h] = acc[ii][j] + pb1[i * 50 + h];
      }
    }
  }
}

// ---------------- sequential concept sampling: ONE THREAD PER PAIR, software-pipelined across i --------------
// 800 blocks x 256 threads = 204800 pairs exactly (no idle lanes, no barriers, no LDS).
// Dual accumulators: while the serial tail of step i (50-FMA ordered dot -> sigmoid -> threefry
// -> compare) is in flight, the r-loop for step i+1 runs over rows 0..i-1 (bits already known);
// row i is added after the sample lands (fmaf with c in {0,1} -> bitwise identical to the
// straight-line version). Weight rows are consumed in two 25-dword h-chunks so the compiler can
// double-buffer the wave-uniform scalar loads inside the 102-SGPR file (a 50-dword row + a
// prefetched row cannot both fit, which serialized the old r-loop on s_load latency).
// Per-h accumulation order (r ascending) and the tail arithmetic are EXACTLY those of the
// validated kernel, so sampling cannot flip.
// c_hard is not written here; the two u64 history masks go to the never-staged m>=50 cells of
// c_hard rows 0..7 (expand_kernel materializes c_hard afterwards).
__global__ __launch_bounds__(256, 3) void sample_kernel3(const float* __restrict__ W1,
                                                         const float* __restrict__ W2,
                                                         const float* __restrict__ b2v,
                                                         float* __restrict__ out, SKeys sks) {
  const int t = threadIdx.x;
  const int p = blockIdx.x * 256 + t;         // pair id = b*100 + m, exact cover
  const int b = p / 100;
  const int m = p - b * 100;
  const float* __restrict__ baserow = out + CHOFF + (size_t)b * 11200;  // + i*100 + h
  u64 lo = 0, hi = 0;
  float accA[50], accB[50];
#pragma unroll
  for (int h = 0; h < 50; ++h) accA[h] = 0.f;

#define STEP(I, ACC_C, ACC_N)                                                               \
  {                                                                                         \
    const int i = (I);                                                                      \
    /* 1) build ACC_N = feedback sums for step i+1, rows r=0..i-1 (independent of tail) */  \
    if (i < 111) {                                                                          \
      const float* __restrict__ Wn = W1 + (size_t)(i + 1) * 11200 + 5600;                   \
      _Pragma("unroll")                                                                     \
      for (int h = 0; h < 50; ++h) ACC_N[h] = 0.f;                                          \
      _Pragma("unroll")                                                                     \
      for (int half = 0; half < 2; ++half) {                                                \
        const float* __restrict__ Wh = Wn + half * 25;                                      \
        int r = 0;                                                                          \
        int r1 = (i < 64) ? i : 64;                                                         \
        u64 cm = lo;                                                                        \
        for (; r < r1; ++r) {                                                               \
          float c = (cm & 1ull) ? 1.f : 0.f;                                                \
          cm >>= 1;                                                                         \
          const float* __restrict__ wr = Wh + r * 50;  /* wave-uniform -> s_load x25 */     \
          _Pragma("unroll")                                                                 \
          for (int h = 0; h < 25; ++h)                                                      \
            ACC_N[half * 25 + h] = fmaf(c, wr[h], ACC_N[half * 25 + h]);                    \
        }                                                                                   \
        cm = hi;                                                                            \
        for (; r < i; ++r) {                                                                \
          float c = (cm & 1ull) ? 1.f : 0.f;                                                \
          cm >>= 1;                                                                         \
          const float* __restrict__ wr = Wh + r * 50;                                       \
          _Pragma("unroll")                                                                 \
          for (int h = 0; h < 25; ++h)                                                      \
            ACC_N[half * 25 + h] = fmaf(c, wr[h], ACC_N[half * 25 + h]);                    \
        }                                                                                   \
      }                                                                                     \
    }                                                                                       \
    /* 2) tail for step i on ACC_C — arithmetic order identical to validated kernel */      \
    const float* __restrict__ w2 = W2 + i * 50;       /* wave-uniform */                    \
    const float* bs = baserow + (size_t)i * 100;      /* broadcast-friendly per-lane */     \
    float s = 0.f;                                                                          \
    _Pragma("unroll")                                                                       \
    for (int h = 0; h < 50; ++h) {                                                          \
      float v = ACC_C[h] + bs[h];                                                           \
      if (v < 0.f) v = 0.01f * v;                                                           \
      s = fmaf(v, w2[h], s);                                                                \
    }                                                                                       \
    float l = s + b2v[i];                                                                   \
    float pr = 1.f / (1.f + expf(-l));                                                      \
    u32 a0, a1;                                                                             \
    tf2x32(sks.v[2 * i], sks.v[2 * i + 1], 0u, (u32)p, a0, a1);                             \
    u32 fb = ((a0 ^ a1) >> 9) | 0x3F800000u;                                                \
    float uu; __builtin_memcpy(&uu, &fb, 4); uu -= 1.f;                                     \
    float cbit = (uu < pr) ? 1.f : 0.f;                                                     \
    out[(size_t)b * 11200 + (size_t)i * 100 + m] = pr;   /* c_prob (owned cell) */          \
    {                                                                                       \
      u64 sbit = (uu < pr) ? 1ull : 0ull;                                                   \
      if (i < 64) lo |= sbit << i; else hi |= sbit << (i - 64);                             \
    }                                                                                       \
    /* 3) late row r=i for step i+1 (fmaf with c in {0,1}: bitwise = ordered r-loop) */     \
    if (i < 111) {                                                                          \
      const float* __restrict__ wr = W1 + (size_t)(i + 1) * 11200 + 5600 + (size_t)i * 50;  \
      _Pragma("unroll")                                                                     \
      for (int h = 0; h < 50; ++h) ACC_N[h] = fmaf(cbit, wr[h], ACC_N[h]);                  \
    }                                                                                       \
  }

  for (int i0 = 0; i0 < 112; i0 += 2) {
    STEP(i0, accA, accB)
    STEP(i0 + 1, accB, accA)
  }
#undef STEP

  // store the two u64 masks into the never-staged m>=50 cells of c_hard rows 0..7
  {
    u32* ob = (u32*)out;
    size_t cb = CHOFF + (size_t)b * 11200 + (size_t)((m >= 50) ? 4 : 0) * 100 + 50 + (m % 50);
    ob[cb + 0]   = (u32)lo;
    ob[cb + 100] = (u32)(lo >> 32);
    ob[cb + 200] = (u32)hi;
    ob[cb + 300] = (u32)(hi >> 32);
  }
}

// ---------------- expand masks -> c_hard (memory-bound, ~30 us) ----------------
// one block per batch b; reads the packed masks (before any write), then writes all 11200 cells
__global__ __launch_bounds__(256) void expand_kernel(float* __restrict__ out) {
  __shared__ u32 mW[100][4];
  const int b = blockIdx.x;
  const int t = threadIdx.x;
  const u32* ob = (const u32*)out;
  if (t < 100) {
    size_t cb = CHOFF + (size_t)b * 11200 + (size_t)((t >= 50) ? 4 : 0) * 100 + 50 + (t % 50);
    mW[t][0] = ob[cb + 0];
    mW[t][1] = ob[cb + 100];
    mW[t][2] = ob[cb + 200];
    mW[t][3] = ob[cb + 300];
  }
  __syncthreads();
  for (int e = t; e < 11200; e += 256) {
    int i = e / 100, m = e - i * 100;
    u32 word = mW[m][i >> 5];
    out[CHOFF + (size_t)b * 11200 + e] = (float)((word >> (i & 31)) & 1u);
  }
}

// ---------------- head: logits -> softmax -> mean over m -> log ----------------
// one block per b; 256 threads
__global__ __launch_bounds__(256) void head_kernel(const float* __restrict__ HW,
                                                   const float* __restrict__ hb,
                                                   float* __restrict__ out) {
  __shared__ unsigned char cS[100][116];
  __shared__ float lgS[50][201];
  const int b = blockIdx.x;
  const int t = threadIdx.x;
  for (int e = t; e < 11200; e += 256) {
    int k = e / 100, m = e - k * 100;
    cS[m][k] = (out[CHOFF + (size_t)b * 11200 + (size_t)k * 100 + m] != 0.f) ? 1 : 0;
  }
  __syncthreads();
  float pacc = 0.f;
  for (int mh = 0; mh < 2; ++mh) {
    for (int l = 0; l < 3; ++l) {
      int tile = l * 256 + t;
      if (tile < 625) {                    // 25 o-chunks x 25 m-chunks
        int o0 = (tile % 25) * 8;
        int m0 = (tile / 25) * 2;
        float acc[2][8] = {};
        for (int k = 0; k < 112; ++k) {
          float4 wa = *(const float4*)(HW + (size_t)k * 200 + o0);
          float4 wb = *(const float4*)(HW + (size_t)k * 200 + o0 + 4);
          float w[8] = {wa.x, wa.y, wa.z, wa.w, wb.x, wb.y, wb.z, wb.w};
          float c0 = (float)cS[mh * 50 + m0][k];
          float c1 = (float)cS[mh * 50 + m0 + 1][k];
#pragma unroll
          for (int jo = 0; jo < 8; ++jo) {
            acc[0][jo] = fmaf(c0, w[jo], acc[0][jo]);
            acc[1][jo] = fmaf(c1, w[jo], acc[1][jo]);
          }
        }
#pragma unroll
        for (int im = 0; im < 2; ++im)
#pragma unroll
          for (int jo = 0; jo < 8; ++jo) {
            int o = o0 + jo;
            lgS[m0 + im][o] = acc[im][jo] + hb[o];
          }
      }
    }
    __syncthreads();
    if (t < 50) {
      int m = t;
      float mx = -3.0e38f;
      for (int o = 0; o < 200; ++o) mx = fmaxf(mx, lgS[m][o]);
      float s = 0.f;
      for (int o = 0; o < 200; ++o) {
        float e = expf(lgS[m][o] - mx);
        lgS[m][o] = e; s += e;
      }
      float inv = 1.f / s;
      for (int o = 0; o < 200; ++o) lgS[m][o] = lgS[m][o] * inv;
    }
    __syncthreads();
    if (t < 200) { for (int m = 0; m < 50; ++m) pacc += lgS[m][t]; }
    __syncthreads();
  }
  if (t < 200) {
    out[YOFF + (size_t)b * 200 + t] = logf(pacc / 100.f + 1e-6f);
  }
}

// ---------------- launcher ----------------
extern "C" void kernel_launch(void* const* d_in, const int* in_sizes, int n_in,
                              void* d_out, int out_size, void* d_ws, size_t ws_size,
                              hipStream_t stream) {
  const float* x    = (const float*)d_in[0];
  const float* Win  = (const float*)d_in[1];
  const float* bin  = (const float*)d_in[2];
  const float* Wh   = (const float*)d_in[3];
  const float* bh   = (const float*)d_in[4];
  const float* Wout = (const float*)d_in[5];
  const float* bout = (const float*)d_in[6];
  const float* pW1  = (const float*)d_in[7];
  const float* pb1  = (const float*)d_in[8];
  const float* pW2  = (const float*)d_in[9];
  const float* pb2  = (const float*)d_in[10];
  const float* hW   = (const float*)d_in[11];
  const float* hb   = (const float*)d_in[12];
  float* out = (float*)d_out;
  char* ws = (char*)d_ws;

  float* hA     = (float*)(ws + OFF_HA);
  float* hB     = (float*)(ws + OFF_HB);
  float* interB = (float*)(ws + OFF_INTER);

  gemm_bias<true ><<<dim3(8, 32), 256, 0, stream>>>(x,  Win,             bin,          hA,     2048, 512, 256);
  gemm_bias<true ><<<dim3(8, 32), 256, 0, stream>>>(hA, Wh + 0 * 262144, bh + 0 * 512, hB,     2048, 512, 512);
  gemm_bias<true ><<<dim3(8, 32), 256, 0, stream>>>(hB, Wh + 1 * 262144, bh + 1 * 512, hA,     2048, 512, 512);
  gemm_bias<true ><<<dim3(8, 32), 256, 0, stream>>>(hA, Wh + 2 * 262144, bh + 2 * 512, hB,     2048, 512, 512);
  gemm_bias<true ><<<dim3(8, 32), 256, 0, stream>>>(hB, Wh + 3 * 262144, bh + 3 * 512, hA,     2048, 512, 512);
  gemm_bias<false><<<dim3(2, 32), 256, 0, stream>>>(hA, Wout,            bout,         interB, 2048, 112, 512);

  base_kernel<<<dim3(32, 112), 256, 0, stream>>>(interB, pW1, pb1, out);

  // host-side key chain: key(42)=(0,42); partitionable split: key'=tf(key,(0,0)), sk=tf(key,(0,1))
  SKeys sks;
  {
    u32 k0 = 0u, k1 = 42u;
    for (int i = 0; i < 112; ++i) {
      u32 nk0, nk1, s0, s1;
      tf2x32(k0, k1, 0u, 0u, nk0, nk1);
      tf2x32(k0, k1, 0u, 1u, s0, s1);
      sks.v[2 * i] = s0; sks.v[2 * i + 1] = s1;
      k0 = nk0; k1 = nk1;
    }
  }
  sample_kernel3<<<800, 256, 0, stream>>>(pW1, pW2, pb2, out, sks);
  expand_kernel<<<2048, 256, 0, stream>>>(out);

  head_kernel<<<2048, 256, 0, stream>>>(hW, hb, out);
}